// Round 1
// baseline (144.883 us; speedup 1.0000x reference)
//
#include <hip/hip_runtime.h>
#include <hip/hip_bf16.h>

typedef __attribute__((ext_vector_type(4))) float f32x4;
typedef __attribute__((ext_vector_type(8))) short bf16x8;

#define MFMA16(a, b, c) __builtin_amdgcn_mfma_f32_16x16x32_bf16(a, b, c, 0, 0, 0)

constexpr int Bc = 8;
constexpr int Lc = 128;
constexpr int Qc = 8;
constexpr int Hc = 8;
constexpr int Ec = 64;
constexpr int Sc = 128;
constexpr int Pc = 8;
constexpr int NQ = Lc * Qc;   // 1024 query rows per (b,h)
constexpr int NK = Sc * Pc;   // 1024 key rows per (b,h)
constexpr int RS = Hc * Ec;   // 512 floats: row stride in [B, rows, H, E]
constexpr int KT = 64;        // keys per KV tile
constexpr int QT = 64;        // q rows per block (4 waves x 16)
constexpr int VSTR = 72;      // padded LDS stride (bf16 elems), 144B = 16B-aligned rows
constexpr int PSTR = 72;
constexpr float SCALE = 0.125f;  // 1/sqrt(64)

__device__ __forceinline__ short f2bf(float x) {
    __hip_bfloat16 h = __float2bfloat16(x);
    return (short)__builtin_bit_cast(unsigned short, h);
}

__device__ __forceinline__ bf16x8 load_frag_f32(const float* p) {
    // 8 consecutive floats (16B-aligned) -> 8 bf16
    const float4* p4 = (const float4*)p;
    float4 t0 = p4[0];
    float4 t1 = p4[1];
    bf16x8 r;
    r[0] = f2bf(t0.x); r[1] = f2bf(t0.y); r[2] = f2bf(t0.z); r[3] = f2bf(t0.w);
    r[4] = f2bf(t1.x); r[5] = f2bf(t1.y); r[6] = f2bf(t1.z); r[7] = f2bf(t1.w);
    return r;
}

__global__ __launch_bounds__(256, 3)
void fully_attn_kernel(const float* __restrict__ Qg, const float* __restrict__ Kg,
                       const float* __restrict__ Vg, float* __restrict__ Og) {
    // V tile transposed: Vlds[e][key], padded stride
    __shared__ __attribute__((aligned(16))) short Vlds[Ec][VSTR];
    // Per-wave P relayout buffer: Plds[wave][qrow(16)][key(64), padded]
    __shared__ __attribute__((aligned(16))) short Plds[4][16][PSTR];

    const int tid  = threadIdx.x;
    const int lane = tid & 63;
    const int wv   = tid >> 6;   // wave 0..3
    const int c    = lane & 15;  // col / row-within-16
    const int g    = lane >> 4;  // 4-lane-group id 0..3

    const int head = blockIdx.x >> 4;  // 0..63  (b*H + h)
    const int qb   = blockIdx.x & 15;  // q-block 0..15
    const int b    = head >> 3;
    const int h    = head & 7;

    const size_t headQ = (size_t)b * NQ * RS + (size_t)h * Ec;
    const size_t headK = (size_t)b * NK * RS + (size_t)h * Ec;

    // ---- Q fragments (held for whole kernel): rows qb*64 + wv*16 + c ----
    const int qrow = qb * QT + wv * 16 + c;
    const float* qp = Qg + headQ + (size_t)qrow * RS + g * 8;
    const bf16x8 aq0 = load_frag_f32(qp);        // e in [0,32)
    const bf16x8 aq1 = load_frag_f32(qp + 32);   // e in [32,64)

    // Online-softmax state. Lane owns rows g*4+r (r=0..3), col c of each C tile.
    float m_r[4], l_r[4];
    f32x4 o[4];  // O accumulator, e-blocks n=0..3: O[row g*4+r][e = n*16+c]
#pragma unroll
    for (int r = 0; r < 4; ++r) { m_r[r] = -1e30f; l_r[r] = 0.0f; }
#pragma unroll
    for (int n = 0; n < 4; ++n) o[n] = (f32x4)(0.0f);

    for (int t = 0; t < NK / KT; ++t) {
        // ---- stage V tile (transposed, bf16) into LDS ----
        __syncthreads();  // previous tile's Vlds reads complete
#pragma unroll
        for (int it = 0; it < (KT * Ec) / 256; ++it) {
            int idx = it * 256 + tid;
            int key = idx >> 6;   // 0..63
            int e   = idx & 63;   // = lane -> coalesced 256B per row
            float v = Vg[headK + (size_t)(t * KT + key) * RS + e];
            Vlds[e][key] = f2bf(v);
        }
        __syncthreads();

        // ---- S = (Q K^T) * scale for 4 key-subtiles of 16 ----
        f32x4 cs[4];
#pragma unroll
        for (int n = 0; n < 4; ++n) {
            const float* kp = Kg + headK + (size_t)(t * KT + n * 16 + c) * RS + g * 8;
            bf16x8 bk0 = load_frag_f32(kp);
            bf16x8 bk1 = load_frag_f32(kp + 32);
            f32x4 acc = (f32x4)(0.0f);
            acc = MFMA16(aq0, bk0, acc);
            acc = MFMA16(aq1, bk1, acc);
#pragma unroll
            for (int r = 0; r < 4; ++r) cs[n][r] = acc[r] * SCALE;
        }

        // ---- online softmax update ----
#pragma unroll
        for (int r = 0; r < 4; ++r) {
            float v = fmaxf(fmaxf(cs[0][r], cs[1][r]), fmaxf(cs[2][r], cs[3][r]));
            v = fmaxf(v, __shfl_xor(v, 1));
            v = fmaxf(v, __shfl_xor(v, 2));
            v = fmaxf(v, __shfl_xor(v, 4));
            v = fmaxf(v, __shfl_xor(v, 8));
            float mn = fmaxf(m_r[r], v);
            float alpha = __expf(m_r[r] - mn);
            float rsum = 0.0f;
#pragma unroll
            for (int n = 0; n < 4; ++n) {
                float p = __expf(cs[n][r] - mn);
                cs[n][r] = p;
                rsum += p;
            }
            rsum += __shfl_xor(rsum, 1);
            rsum += __shfl_xor(rsum, 2);
            rsum += __shfl_xor(rsum, 4);
            rsum += __shfl_xor(rsum, 8);
            l_r[r] = l_r[r] * alpha + rsum;
            m_r[r] = mn;
#pragma unroll
            for (int n = 0; n < 4; ++n) o[n][r] *= alpha;
        }

        // ---- P: C-layout -> A-layout via per-wave LDS round-trip (bf16) ----
#pragma unroll
        for (int n = 0; n < 4; ++n)
#pragma unroll
            for (int r = 0; r < 4; ++r)
                Plds[wv][g * 4 + r][n * 16 + c] = f2bf(cs[n][r]);
        // same-wave LDS RAW: compiler inserts lgkmcnt waits
        bf16x8 pa0 = *(const bf16x8*)&Plds[wv][c][g * 8];        // keys 0..31
        bf16x8 pa1 = *(const bf16x8*)&Plds[wv][c][32 + g * 8];   // keys 32..63

        // ---- O += P V  (4 e-blocks of 16) ----
#pragma unroll
        for (int n = 0; n < 4; ++n) {
            bf16x8 bv0 = *(const bf16x8*)&Vlds[n * 16 + c][g * 8];
            bf16x8 bv1 = *(const bf16x8*)&Vlds[n * 16 + c][32 + g * 8];
            o[n] = MFMA16(pa0, bv0, o[n]);
            o[n] = MFMA16(pa1, bv1, o[n]);
        }
    }

    // ---- epilogue: O / l ----
    const size_t obase = headQ + (size_t)(qb * QT + wv * 16) * RS;
#pragma unroll
    for (int n = 0; n < 4; ++n) {
#pragma unroll
        for (int r = 0; r < 4; ++r) {
            int row = g * 4 + r;
            float val = o[n][r] / l_r[r];
            Og[obase + (size_t)row * RS + n * 16 + c] = val;
        }
    }
}

extern "C" void kernel_launch(void* const* d_in, const int* in_sizes, int n_in,
                              void* d_out, int out_size, void* d_ws, size_t ws_size,
                              hipStream_t stream) {
    const float* Qg = (const float*)d_in[0];
    const float* Kg = (const float*)d_in[1];
    const float* Vg = (const float*)d_in[2];
    // d_in[3] = attn_mask, unused by the module
    float* Og = (float*)d_out;

    dim3 grid(Bc * Hc * (NQ / QT));  // 8*8*16 = 1024 blocks
    dim3 block(256);
    hipLaunchKernelGGL(fully_attn_kernel, grid, block, 0, stream, Qg, Kg, Vg, Og);
}

// Round 2
// 65.162 us; speedup vs baseline: 2.2234x; 2.2234x over previous
//
#include <hip/hip_runtime.h>
#include <hip/hip_bf16.h>

typedef __attribute__((ext_vector_type(4))) float f32x4;
typedef __attribute__((ext_vector_type(8))) short bf16x8;

#define MFMA16(a, b, c) __builtin_amdgcn_mfma_f32_16x16x32_bf16(a, b, c, 0, 0, 0)

constexpr int Bc = 8, Hc = 8;
constexpr int NQ = 1024;      // L*Q query rows per (b,h)
constexpr int NK = 1024;      // S*P key rows per (b,h)
constexpr int RS = 512;       // H*E floats: row stride
constexpr int Ec = 64;        // head dim
constexpr int KT = 64;        // keys per tile
constexpr int QT = 64;        // q rows per block (4 waves x 16)
constexpr int NT = NK / KT;   // 16 tiles
constexpr float QSCALE = 0.125f;  // 1/sqrt(64), exact pow2 -> folded into Q

__device__ __forceinline__ short f2bf(float x) {
    return (short)__builtin_bit_cast(unsigned short, __float2bfloat16(x));
}

__device__ __forceinline__ bf16x8 pack2(float4 a, float4 b) {
    bf16x8 r;
    r[0] = f2bf(a.x); r[1] = f2bf(a.y); r[2] = f2bf(a.z); r[3] = f2bf(a.w);
    r[4] = f2bf(b.x); r[5] = f2bf(b.y); r[6] = f2bf(b.z); r[7] = f2bf(b.w);
    return r;
}

__device__ __forceinline__ bf16x8 pack2s(float4 a, float4 b, float s) {
    bf16x8 r;
    r[0] = f2bf(a.x * s); r[1] = f2bf(a.y * s); r[2] = f2bf(a.z * s); r[3] = f2bf(a.w * s);
    r[4] = f2bf(b.x * s); r[5] = f2bf(b.y * s); r[6] = f2bf(b.z * s); r[7] = f2bf(b.w * s);
    return r;
}

// LDS tiles: 64 rows x 64 bf16 (128B rows). Element (row, col) stored at
// byte row*128 + ((col*2) ^ ((row&7)<<4))  -- XOR swizzle hits the b128 bank floor.
__global__ __launch_bounds__(256, 4)
void fully_attn_kernel(const float* __restrict__ Qg, const float* __restrict__ Kg,
                       const float* __restrict__ Vg, float* __restrict__ Og) {
    __shared__ __attribute__((aligned(16))) short Kl[2][64][64];  // [key][e]
    __shared__ __attribute__((aligned(16))) short Vl[2][64][64];  // [e][key] (transposed)
    __shared__ __attribute__((aligned(16))) short Pl[4][16][64];  // per-wave [q][key]

    const int tid  = threadIdx.x;
    const int lane = tid & 63;
    const int wv   = tid >> 6;
    const int c    = lane & 15;
    const int g    = lane >> 4;
    const int swzc = (c & 7) << 4;

    // XCD-aware remap: the 16 q-blocks of one head land on the same XCD (bid%8).
    const int bid  = blockIdx.x;
    const int head = (bid & 7) * 8 + (bid >> 7);
    const int qb   = (bid >> 3) & 15;
    const int b    = head >> 3;
    const int h    = head & 7;

    const size_t headQ = (size_t)b * NQ * RS + (size_t)h * Ec;
    const size_t headK = (size_t)b * NK * RS + (size_t)h * Ec;

    // ---- Q fragments, scale folded (exact) ----
    const int qrow = qb * QT + wv * 16 + c;
    const float4* qp4 = (const float4*)(Qg + headQ + (size_t)qrow * RS + g * 8);
    const bf16x8 aq0 = pack2s(qp4[0], qp4[1], QSCALE);  // e in [g*8, g*8+8)
    const bf16x8 aq1 = pack2s(qp4[8], qp4[9], QSCALE);  // e in [32+g*8, ...)

    // ---- staging assignments ----
    const int krow = tid >> 2;        // K: thread loads row krow, e-quarter kq
    const int kq   = tid & 3;
    const int swzk = (krow & 7) << 4;
    const int swzv = (lane & 7) << 4; // V: thread owns Vt row e=lane, key-chunk wv

    float4 kf0, kf1, kf2, kf3;
    float  vf[16];

#define LOAD_TILE(tt)                                                              \
    {                                                                              \
        const float4* kp = (const float4*)(Kg + headK +                            \
                            (size_t)((tt) * KT + krow) * RS + kq * 16);            \
        kf0 = kp[0]; kf1 = kp[1]; kf2 = kp[2]; kf3 = kp[3];                        \
        const float* vp = Vg + headK + (size_t)((tt) * KT + wv * 16) * RS + lane;  \
        _Pragma("unroll")                                                          \
        for (int j = 0; j < 16; ++j) vf[j] = vp[(size_t)j * RS];                   \
    }

#define WRITE_TILE(bufi)                                                           \
    {                                                                              \
        char* kd = (char*)&Kl[bufi][krow][0];                                      \
        *(bf16x8*)(kd + ((kq * 32) ^ swzk))      = pack2(kf0, kf1);                \
        *(bf16x8*)(kd + ((kq * 32 + 16) ^ swzk)) = pack2(kf2, kf3);                \
        bf16x8 w0, w1;                                                             \
        _Pragma("unroll")                                                          \
        for (int j = 0; j < 8; ++j) { w0[j] = f2bf(vf[j]); w1[j] = f2bf(vf[8 + j]); } \
        char* vd = (char*)&Vl[bufi][lane][0];                                      \
        *(bf16x8*)(vd + ((wv * 32) ^ swzv))      = w0;                             \
        *(bf16x8*)(vd + ((wv * 32 + 16) ^ swzv)) = w1;                             \
    }

    // ---- prologue: stage tile 0 ----
    LOAD_TILE(0);
    WRITE_TILE(0);
    __syncthreads();

    float m_r[4], l_r[4];
    f32x4 o[4];
#pragma unroll
    for (int r = 0; r < 4; ++r) { m_r[r] = -1e30f; l_r[r] = 0.0f; }
#pragma unroll
    for (int n = 0; n < 4; ++n) o[n] = (f32x4)(0.0f);

    int cur = 0;
    for (int t = 0; t < NT; ++t) {
        // T14: issue next tile's global loads before compute (latency hides under it)
        if (t + 1 < NT) LOAD_TILE(t + 1);

        // ---- S = Q K^T (scale pre-folded) ----
        f32x4 cs[4];
#pragma unroll
        for (int n = 0; n < 4; ++n) {
            const char* kr = (const char*)&Kl[cur][n * 16 + c][0];
            bf16x8 bk0 = *(const bf16x8*)(kr + ((g * 16) ^ swzc));
            bf16x8 bk1 = *(const bf16x8*)(kr + ((64 + g * 16) ^ swzc));
            f32x4 acc = (f32x4)(0.0f);
            acc = MFMA16(aq0, bk0, acc);
            acc = MFMA16(aq1, bk1, acc);
            cs[n] = acc;
        }

        // ---- online softmax ----
#pragma unroll
        for (int r = 0; r < 4; ++r) {
            float v = fmaxf(fmaxf(cs[0][r], cs[1][r]), fmaxf(cs[2][r], cs[3][r]));
            v = fmaxf(v, __shfl_xor(v, 1));
            v = fmaxf(v, __shfl_xor(v, 2));
            v = fmaxf(v, __shfl_xor(v, 4));
            v = fmaxf(v, __shfl_xor(v, 8));
            float mn = fmaxf(m_r[r], v);
            float alpha = __expf(m_r[r] - mn);
            float rsum = 0.0f;
#pragma unroll
            for (int n = 0; n < 4; ++n) {
                float p = __expf(cs[n][r] - mn);
                cs[n][r] = p;
                rsum += p;
            }
            rsum += __shfl_xor(rsum, 1);
            rsum += __shfl_xor(rsum, 2);
            rsum += __shfl_xor(rsum, 4);
            rsum += __shfl_xor(rsum, 8);
            l_r[r] = l_r[r] * alpha + rsum;
            m_r[r] = mn;
#pragma unroll
            for (int n = 0; n < 4; ++n) o[n][r] *= alpha;
        }

        // ---- P: C-layout -> A-layout via per-wave swizzled LDS round-trip ----
#pragma unroll
        for (int n = 0; n < 4; ++n)
#pragma unroll
            for (int r = 0; r < 4; ++r) {
                const int row = g * 4 + r;
                *(short*)((char*)&Pl[wv][row][0] +
                          ((n * 32 + c * 2) ^ ((row & 7) << 4))) = f2bf(cs[n][r]);
            }
        const char* pr = (const char*)&Pl[wv][c][0];
        bf16x8 pa0 = *(const bf16x8*)(pr + ((g * 16) ^ swzc));
        bf16x8 pa1 = *(const bf16x8*)(pr + ((64 + g * 16) ^ swzc));

        // ---- O += P V ----
#pragma unroll
        for (int n = 0; n < 4; ++n) {
            const char* vr = (const char*)&Vl[cur][n * 16 + c][0];
            bf16x8 bv0 = *(const bf16x8*)(vr + ((g * 16) ^ swzc));
            bf16x8 bv1 = *(const bf16x8*)(vr + ((64 + g * 16) ^ swzc));
            o[n] = MFMA16(pa0, bv0, o[n]);
            o[n] = MFMA16(pa1, bv1, o[n]);
        }

        // ---- write next tile into the other buffer (overlaps other waves' compute) ----
        if (t + 1 < NT) WRITE_TILE(cur ^ 1);
        __syncthreads();
        cur ^= 1;
    }

    // ---- epilogue ----
    const size_t obase = headQ + (size_t)(qb * QT + wv * 16) * RS;
#pragma unroll
    for (int n = 0; n < 4; ++n)
#pragma unroll
        for (int r = 0; r < 4; ++r) {
            const int row = g * 4 + r;
            Og[obase + (size_t)row * RS + n * 16 + c] = o[n][r] / l_r[r];
        }
}

extern "C" void kernel_launch(void* const* d_in, const int* in_sizes, int n_in,
                              void* d_out, int out_size, void* d_ws, size_t ws_size,
                              hipStream_t stream) {
    const float* Qg = (const float*)d_in[0];
    const float* Kg = (const float*)d_in[1];
    const float* Vg = (const float*)d_in[2];
    float* Og = (float*)d_out;

    dim3 grid(Bc * Hc * (NQ / QT));  // 1024 blocks
    dim3 block(256);
    hipLaunchKernelGGL(fully_attn_kernel, grid, block, 0, stream, Qg, Kg, Vg, Og);
}